// Round 2
// baseline (140.368 us; speedup 1.0000x reference)
//
#include <hip/hip_runtime.h>
#include <hip/hip_bf16.h>

namespace {

constexpr int kC = 32;
constexpr int kD = 512;
constexpr int kB = 512;
constexpr int kN = 1024;               // 2B rows (source ++ target)
constexpr int kCD = kC * kD;           // floats per batch index i
constexpr int BM = 128;                // tile rows/cols
constexpr int BK = 64;                 // K chunk
constexpr int KSTEPS = kD / BK;        // 8
constexpr int TILES = kN / BM;         // 8
constexpr int NPAIRS = TILES * (TILES + 1) / 2;  // 36 (ti <= tj)

typedef float f32x4 __attribute__((ext_vector_type(4)));
typedef short s16x8 __attribute__((ext_vector_type(8)));

// pack two f32 to bf16 (RNE) into one u32: a -> low half, b -> high half
__device__ inline unsigned int pack_bf16(float a, float b) {
  unsigned int ua = __float_as_uint(a);
  unsigned int ub = __float_as_uint(b);
  ua += 0x7fffu + ((ua >> 16) & 1u);   // round-to-nearest-even
  ub += 0x7fffu + ((ub >> 16) & 1u);
  return (ua >> 16) | (ub & 0xffff0000u);
}

// sq[c*kN + i] = sum_d total[i,c,d]^2   (f32, from original f32 inputs)
__global__ void sq_kernel(const float* __restrict__ src,
                          const float* __restrict__ tgt,
                          float* __restrict__ sq) {
  int gw = (blockIdx.x * blockDim.x + threadIdx.x) >> 6;  // one wave per (i,c)
  int lane = threadIdx.x & 63;
  if (gw >= kN * kC) return;
  int i = gw >> 5;
  int c = gw & 31;
  const float* p = (i < kB ? src + (size_t)i * kCD
                           : tgt + (size_t)(i - kB) * kCD) + c * kD;
  float4 v0 = *(const float4*)(p + lane * 4);
  float4 v1 = *(const float4*)(p + 256 + lane * 4);
  float s = v0.x * v0.x + v0.y * v0.y + v0.z * v0.z + v0.w * v0.w
          + v1.x * v1.x + v1.y * v1.y + v1.z * v1.z + v1.w * v1.w;
#pragma unroll
  for (int o = 32; o > 0; o >>= 1) s += __shfl_down(s, o);
  if (lane == 0) sq[c * kN + i] = s;
}

// One block per (pair(ti<=tj), c). Computes 128x128 tile of cross for channel
// c via bf16 MFMA, applies the 5-sigma kernel epilogue, reduces, atomicAdd.
__launch_bounds__(256, 2)
__global__ void mmd_kernel(const float* __restrict__ src,
                           const float* __restrict__ tgt,
                           const float* __restrict__ sq,
                           float* __restrict__ out) {
  // decode triangular pair index
  int p = blockIdx.x;
  int c = blockIdx.y;
  int ti = 0;
  while (p >= TILES - ti) { p -= TILES - ti; ++ti; }
  int tj = ti + p;

  __shared__ __align__(16) unsigned short lA[2][BM * BK];  // bf16 bits, swizzled
  __shared__ __align__(16) unsigned short lB[2][BM * BK];
  __shared__ float wsum[4];

  const int t = threadIdx.x;
  const int lane = t & 63;
  const int wid = t >> 6;
  const int wr = wid >> 1;   // wave row (0..1)
  const int wc = wid & 1;    // wave col (0..1)

  // staging: thread t owns row r = t>>1, cols 32*(t&1)..+31 (f32) of A and B
  const int r = t >> 1;
  const int h = t & 1;
  const int ia = ti * BM + r;
  const int ib = tj * BM + r;
  const float* pA = (ia < kB ? src + (size_t)ia * kCD
                             : tgt + (size_t)(ia - kB) * kCD) + c * kD + h * 32;
  const float* pB = (ib < kB ? src + (size_t)ib * kCD
                             : tgt + (size_t)(ib - kB) * kCD) + c * kD + h * 32;

  float4 ra[8], rb[8];

  auto LOAD = [&](int ks) {
    const float4* qa = (const float4*)(pA + ks * BK);
    const float4* qb = (const float4*)(pB + ks * BK);
#pragma unroll
    for (int q = 0; q < 8; ++q) { ra[q] = qa[q]; rb[q] = qb[q]; }
  };

  // write 32 bf16 per matrix per thread; 16B chunks, XOR-swizzled slot
  auto STORE = [&](int buf) {
    uint4* A4 = (uint4*)lA[buf];
    uint4* B4 = (uint4*)lB[buf];
#pragma unroll
    for (int sl = 0; sl < 4; ++sl) {
      int slot = r * 8 + (((h << 2) + sl) ^ (r & 7));
      float4 u0 = ra[2 * sl], u1 = ra[2 * sl + 1];
      A4[slot] = make_uint4(pack_bf16(u0.x, u0.y), pack_bf16(u0.z, u0.w),
                            pack_bf16(u1.x, u1.y), pack_bf16(u1.z, u1.w));
      float4 v0 = rb[2 * sl], v1 = rb[2 * sl + 1];
      B4[slot] = make_uint4(pack_bf16(v0.x, v0.y), pack_bf16(v0.z, v0.w),
                            pack_bf16(v1.x, v1.y), pack_bf16(v1.z, v1.w));
    }
  };

  f32x4 acc[4][4] = {};

  LOAD(0);
  STORE(0);
  __syncthreads();

  for (int ks = 0; ks < KSTEPS; ++ks) {
    const int cur = ks & 1;
    if (ks + 1 < KSTEPS) LOAD(ks + 1);

    const s16x8* A8 = (const s16x8*)lA[cur];
    const s16x8* B8 = (const s16x8*)lB[cur];
#pragma unroll
    for (int kk = 0; kk < 2; ++kk) {
      s16x8 aF[4], bF[4];
#pragma unroll
      for (int m = 0; m < 4; ++m) {
        int row = wr * 64 + m * 16 + (lane & 15);
        aF[m] = A8[row * 8 + ((kk * 4 + (lane >> 4)) ^ (row & 7))];
      }
#pragma unroll
      for (int n = 0; n < 4; ++n) {
        int row = wc * 64 + n * 16 + (lane & 15);
        bF[n] = B8[row * 8 + ((kk * 4 + (lane >> 4)) ^ (row & 7))];
      }
#pragma unroll
      for (int m = 0; m < 4; ++m)
#pragma unroll
        for (int n = 0; n < 4; ++n)
          acc[m][n] = __builtin_amdgcn_mfma_f32_16x16x32_bf16(
              aF[m], bF[n], acc[m][n], 0, 0, 0);
    }

    if (ks + 1 < KSTEPS) {
      STORE(cur ^ 1);
      __syncthreads();
    }
  }

  // epilogue: L2 = sq_i + sq_j - 2*cross; kernel-sum via repeated squaring
  const float sA = (ti < TILES / 2) ? 1.f : -1.f;
  const float sB = (tj < TILES / 2) ? 1.f : -1.f;
  const float scale = sA * sB * ((ti == tj) ? 1.f : 2.f) / 262144.f;  // /B^2
  const float* sqA = sq + c * kN + ti * BM;
  const float* sqB = sq + c * kN + tj * BM;

  float local = 0.f;
#pragma unroll
  for (int m = 0; m < 4; ++m) {
    float sqa_r[4];
#pragma unroll
    for (int rI = 0; rI < 4; ++rI)
      sqa_r[rI] = sqA[wr * 64 + m * 16 + (lane >> 4) * 4 + rI];
#pragma unroll
    for (int n = 0; n < 4; ++n) {
      float sqb_ = sqB[wc * 64 + n * 16 + (lane & 15)];
#pragma unroll
      for (int rI = 0; rI < 4; ++rI) {
        float L2 = sqa_r[rI] + sqb_ - 2.f * acc[m][n][rI];
        float tt = __expf(L2 * -0.0625f);  // exp(-L2/16)
        float t2 = tt * tt, t4 = t2 * t2, t8 = t4 * t4;
        local += tt + t2 + t4 + t8 + t8 * t8;
      }
    }
  }

#pragma unroll
  for (int o = 32; o > 0; o >>= 1) local += __shfl_down(local, o);
  if (lane == 0) wsum[wid] = local;
  __syncthreads();
  if (t == 0)
    atomicAdd(out, (wsum[0] + wsum[1] + wsum[2] + wsum[3]) * scale);
}

}  // namespace

extern "C" void kernel_launch(void* const* d_in, const int* in_sizes, int n_in,
                              void* d_out, int out_size, void* d_ws,
                              size_t ws_size, hipStream_t stream) {
  const float* src = (const float*)d_in[0];
  const float* tgt = (const float*)d_in[1];
  float* out = (float*)d_out;
  float* sq = (float*)d_ws;  // needs kN*kC*4 = 128 KiB of workspace

  (void)hipMemsetAsync(d_out, 0, sizeof(float), stream);

  {
    int waves = kN * kC;            // one wave per (i,c) row
    int blocks = waves / 4;         // 256 threads = 4 waves
    sq_kernel<<<blocks, 256, 0, stream>>>(src, tgt, sq);
  }
  {
    dim3 grid(NPAIRS, kC);
    mmd_kernel<<<grid, 256, 0, stream>>>(src, tgt, sq, out);
  }
}

// Round 3
// 59.915 us; speedup vs baseline: 2.3428x; 2.3428x over previous
//
#include <hip/hip_runtime.h>

namespace {

constexpr int kC = 32;
constexpr int kD = 512;
constexpr int kB = 512;
constexpr int kN = 1024;               // 2B rows (source ++ target)
constexpr int kCD = kC * kD;           // floats per batch index i
constexpr int BM = 128;                // tile rows/cols
constexpr int BK = 64;                 // K chunk (bf16 elements)
constexpr int KSTEPS = kD / BK;        // 8
constexpr int TILES = kN / BM;         // 8
constexpr int NPAIRS = TILES * (TILES + 1) / 2;  // 36 (ti <= tj)

typedef float f32x4 __attribute__((ext_vector_type(4)));
typedef short s16x8 __attribute__((ext_vector_type(8)));

// pack two f32 to bf16 (RNE) into one u32: a -> low half, b -> high half
__device__ inline unsigned int pack_bf16(float a, float b) {
  unsigned int ua = __float_as_uint(a);
  unsigned int ub = __float_as_uint(b);
  ua += 0x7fffu + ((ua >> 16) & 1u);   // round-to-nearest-even
  ub += 0x7fffu + ((ub >> 16) & 1u);
  return (ua >> 16) | (ub & 0xffff0000u);
}

// Pass 1: tot[c][i][d] = bf16(total[i,c,d]); sq[c*kN+i] = sum_d total^2 (f32).
// One wave per (i,c) row of 512 floats.
__global__ void prep_kernel(const float* __restrict__ src,
                            const float* __restrict__ tgt,
                            float* __restrict__ sq,
                            unsigned int* __restrict__ tot) {
  int gw = (blockIdx.x * blockDim.x + threadIdx.x) >> 6;
  int lane = threadIdx.x & 63;
  int i = gw >> 5;
  int c = gw & 31;
  const float* p = (i < kB ? src + (size_t)i * kCD
                           : tgt + (size_t)(i - kB) * kCD) + c * kD;
  f32x4 v0 = *(const f32x4*)(p + lane * 8);
  f32x4 v1 = *(const f32x4*)(p + lane * 8 + 4);

  uint4 w = make_uint4(pack_bf16(v0.x, v0.y), pack_bf16(v0.z, v0.w),
                       pack_bf16(v1.x, v1.y), pack_bf16(v1.z, v1.w));
  // row base (in u32 units): (c*kN + i) * kD/2 ; lane covers 4 u32 = 8 bf16
  *(uint4*)(tot + (size_t)(c * kN + i) * (kD / 2) + lane * 4) = w;

  float s = v0.x * v0.x + v0.y * v0.y + v0.z * v0.z + v0.w * v0.w
          + v1.x * v1.x + v1.y * v1.y + v1.z * v1.z + v1.w * v1.w;
#pragma unroll
  for (int o = 32; o > 0; o >>= 1) s += __shfl_down(s, o);
  if (lane == 0) sq[c * kN + i] = s;
}

// Pass 2: one block per (pair(ti<=tj), c); b%8 == c%8 pins channel -> XCD.
__launch_bounds__(256, 2)
__global__ void mmd_kernel(const unsigned short* __restrict__ tot,
                           const float* __restrict__ sq,
                           float* __restrict__ out) {
  int b = blockIdx.x;
  int c = b & 31;           // b = pair*32 + c  -> b%8 == c%8 (XCD pin)
  int p = b >> 5;
  int ti = 0;
  while (p >= TILES - ti) { p -= TILES - ti; ++ti; }
  int tj = ti + p;

  // Linear row-major [128 rows][128 B]; chunk k of row r lives at slot k^(r&7).
  __shared__ __align__(16) unsigned short lA[2][BM * BK];
  __shared__ __align__(16) unsigned short lB[2][BM * BK];
  __shared__ float wsum[4];

  const int t = threadIdx.x;
  const int lane = t & 63;
  const int wid = t >> 6;
  const int wr = wid >> 1;   // wave row (0..1)
  const int wc = wid & 1;    // wave col (0..1)

  const unsigned short* gA = tot + (size_t)(c * kN + ti * BM) * kD;
  const unsigned short* gB = tot + (size_t)(c * kN + tj * BM) * kD;

  // staging geometry: wave 'wid', call q covers LDS bytes (q*4+wid)*1024..+1023
  // lane l -> lds offset base + l*16 -> row=(q*4+wid)*8 + (l>>3), slot=l&7.
  const int srow = lane >> 3;
  const int sslot = lane & 7;

  auto STAGE = [&](int buf, int ks) {
#pragma unroll
    for (int q = 0; q < 4; ++q) {
      int row = (q * 4 + wid) * 8 + srow;
      int chunk = sslot ^ (row & 7);   // inverse-swizzle the SOURCE
      const unsigned short* sa = gA + (size_t)row * kD + ks * BK + chunk * 8;
      const unsigned short* sb = gB + (size_t)row * kD + ks * BK + chunk * 8;
      __builtin_amdgcn_global_load_lds(
          (const __attribute__((address_space(1))) unsigned int*)sa,
          (__attribute__((address_space(3))) unsigned int*)&lA[buf][(q * 4 + wid) * 512],
          16, 0, 0);
      __builtin_amdgcn_global_load_lds(
          (const __attribute__((address_space(1))) unsigned int*)sb,
          (__attribute__((address_space(3))) unsigned int*)&lB[buf][(q * 4 + wid) * 512],
          16, 0, 0);
    }
  };

  f32x4 acc[4][4] = {};

  STAGE(0, 0);
  __syncthreads();

  int cur = 0;
  for (int ks = 0; ks < KSTEPS; ++ks) {
    if (ks + 1 < KSTEPS) STAGE(cur ^ 1, ks + 1);

    const s16x8* A8 = (const s16x8*)lA[cur];
    const s16x8* B8 = (const s16x8*)lB[cur];
#pragma unroll
    for (int kk = 0; kk < 2; ++kk) {
      s16x8 aF[4], bF[4];
#pragma unroll
      for (int m = 0; m < 4; ++m) {
        int row = wr * 64 + m * 16 + (lane & 15);
        aF[m] = A8[row * 8 + ((kk * 4 + (lane >> 4)) ^ (row & 7))];
      }
#pragma unroll
      for (int n = 0; n < 4; ++n) {
        int row = wc * 64 + n * 16 + (lane & 15);
        bF[n] = B8[row * 8 + ((kk * 4 + (lane >> 4)) ^ (row & 7))];
      }
#pragma unroll
      for (int m = 0; m < 4; ++m)
#pragma unroll
        for (int n = 0; n < 4; ++n)
          acc[m][n] = __builtin_amdgcn_mfma_f32_16x16x32_bf16(
              aF[m], bF[n], acc[m][n], 0, 0, 0);
    }

    __syncthreads();   // drains vmcnt(0)+lgkmcnt(0): next buffer ready
    cur ^= 1;
  }

  // epilogue: L2 = sq_i + sq_j - 2*cross; 5-sigma kernel via repeated squaring
  const float sA = (ti < TILES / 2) ? 1.f : -1.f;
  const float sB = (tj < TILES / 2) ? 1.f : -1.f;
  const float scale = sA * sB * ((ti == tj) ? 1.f : 2.f) / 262144.f;  // /B^2
  const float* sqA = sq + c * kN + ti * BM;
  const float* sqB = sq + c * kN + tj * BM;

  float local = 0.f;
#pragma unroll
  for (int m = 0; m < 4; ++m) {
    float sqa_r[4];
#pragma unroll
    for (int rI = 0; rI < 4; ++rI)
      sqa_r[rI] = sqA[wr * 64 + m * 16 + (lane >> 4) * 4 + rI];
#pragma unroll
    for (int n = 0; n < 4; ++n) {
      float sqb_ = sqB[wc * 64 + n * 16 + (lane & 15)];
#pragma unroll
      for (int rI = 0; rI < 4; ++rI) {
        float L2 = sqa_r[rI] + sqb_ - 2.f * acc[m][n][rI];
        float tt = __expf(L2 * -0.0625f);  // exp(-L2/16)
        float t2 = tt * tt, t4 = t2 * t2, t8 = t4 * t4;
        local += tt + t2 + t4 + t8 + t8 * t8;
      }
    }
  }

#pragma unroll
  for (int o = 32; o > 0; o >>= 1) local += __shfl_down(local, o);
  if (lane == 0) wsum[wid] = local;
  __syncthreads();
  if (t == 0)
    atomicAdd(out, (wsum[0] + wsum[1] + wsum[2] + wsum[3]) * scale);
}

}  // namespace

extern "C" void kernel_launch(void* const* d_in, const int* in_sizes, int n_in,
                              void* d_out, int out_size, void* d_ws,
                              size_t ws_size, hipStream_t stream) {
  const float* src = (const float*)d_in[0];
  const float* tgt = (const float*)d_in[1];
  float* out = (float*)d_out;

  // workspace layout: [sq: 32*1024 f32 = 128 KiB][tot bf16: 32*1024*512*2 = 32 MiB]
  float* sq = (float*)d_ws;
  unsigned int* tot = (unsigned int*)((char*)d_ws + (size_t)kC * kN * 4);

  (void)hipMemsetAsync(d_out, 0, sizeof(float), stream);

  {
    int blocks = (kN * kC) / 4;   // one wave per (i,c) row, 4 waves/block
    prep_kernel<<<blocks, 256, 0, stream>>>(src, tgt, sq, tot);
  }
  {
    mmd_kernel<<<NPAIRS * kC, 256, 0, stream>>>((const unsigned short*)tot, sq, out);
  }
}

// Round 4
// 53.800 us; speedup vs baseline: 2.6090x; 1.1137x over previous
//
#include <hip/hip_runtime.h>

namespace {

constexpr int kC = 32;
constexpr int kD = 512;
constexpr int kB = 512;
constexpr int kN = 1024;               // 2B rows (source ++ target)
constexpr int kCD = kC * kD;           // floats per batch index i
constexpr int BM = 128;                // tile rows/cols
constexpr int BK = 32;                 // K chunk (bf16 elements)
constexpr int KSTEPS = kD / BK;        // 16
constexpr int TILES = kN / BM;         // 8
constexpr int NPAIRS = TILES * (TILES + 1) / 2;  // 36 (ti <= tj)

typedef float f32x4 __attribute__((ext_vector_type(4)));
typedef short s16x8 __attribute__((ext_vector_type(8)));

// pack two f32 to bf16 (RNE) into one u32: a -> low half, b -> high half
__device__ inline unsigned int pack_bf16(float a, float b) {
  unsigned int ua = __float_as_uint(a);
  unsigned int ub = __float_as_uint(b);
  ua += 0x7fffu + ((ua >> 16) & 1u);   // round-to-nearest-even
  ub += 0x7fffu + ((ub >> 16) & 1u);
  return (ua >> 16) | (ub & 0xffff0000u);
}

// Pass 1: tot[c][i][d] = bf16(total[i,c,d]); sq[c*kN+i] = sum_d total^2 (f32).
// One wave per (i,c) row of 512 floats. Also zeroes d_out (replaces memset).
__global__ void prep_kernel(const float* __restrict__ src,
                            const float* __restrict__ tgt,
                            float* __restrict__ sq,
                            unsigned int* __restrict__ tot,
                            float* __restrict__ out) {
  if (blockIdx.x == 0 && threadIdx.x == 0) *out = 0.f;
  int gw = (blockIdx.x * blockDim.x + threadIdx.x) >> 6;
  int lane = threadIdx.x & 63;
  int i = gw >> 5;
  int c = gw & 31;
  const float* p = (i < kB ? src + (size_t)i * kCD
                           : tgt + (size_t)(i - kB) * kCD) + c * kD;
  f32x4 v0 = *(const f32x4*)(p + lane * 8);
  f32x4 v1 = *(const f32x4*)(p + lane * 8 + 4);

  uint4 w = make_uint4(pack_bf16(v0.x, v0.y), pack_bf16(v0.z, v0.w),
                       pack_bf16(v1.x, v1.y), pack_bf16(v1.z, v1.w));
  *(uint4*)(tot + (size_t)(c * kN + i) * (kD / 2) + lane * 4) = w;

  float s = v0.x * v0.x + v0.y * v0.y + v0.z * v0.z + v0.w * v0.w
          + v1.x * v1.x + v1.y * v1.y + v1.z * v1.z + v1.w * v1.w;
#pragma unroll
  for (int o = 32; o > 0; o >>= 1) s += __shfl_down(s, o);
  if (lane == 0) sq[c * kN + i] = s;
}

// Pass 2: one block per (pair(ti<=tj), c); b%8 == c%8 pins channel -> XCD.
// LDS layout (per 8KB buffer, row r in 0..127, 16B chunk c in 0..3 of the
// 64B row): byte S(r,c) = (r>>1)*128 + (r&1)*64 + (c ^ ((r>>1)&3))*16.
// 16B-granular swizzle -> global_load_lds sources stay contiguous; ds_read
// of a fragment column spreads 16 lanes over 8 distinct 16B slots (2-way).
__launch_bounds__(256, 4)
__global__ void mmd_kernel(const unsigned short* __restrict__ tot,
                           const float* __restrict__ sq,
                           float* __restrict__ out) {
  int b = blockIdx.x;
  int c = b & 31;           // b = pair*32 + c  -> b%8 == c%8 (XCD pin)
  int p = b >> 5;
  int ti = 0;
  while (p >= TILES - ti) { p -= TILES - ti; ++ti; }
  int tj = ti + p;

  __shared__ __align__(16) unsigned short lA[2][BM * BK];  // 2 x 8KB
  __shared__ __align__(16) unsigned short lB[2][BM * BK];
  __shared__ float wsum[4];

  const int t = threadIdx.x;
  const int lane = t & 63;
  const int wid = t >> 6;
  const int wr = wid >> 1;   // wave row (0..1)
  const int wc = wid & 1;    // wave col (0..1)

  const unsigned short* gA = tot + (size_t)(c * kN + ti * BM) * kD;
  const unsigned short* gB = tot + (size_t)(c * kN + tj * BM) * kD;

  // staging geometry: instr i covers LDS bytes [i*1024, +1024); lane l's 16B
  // at linear o=i*1024+l*16 must hold global row r, chunk cch (see S above):
  const int srow = ((lane >> 3) << 1) + ((lane >> 2) & 1);  // + 16*i
  const int scch = (lane & 3) ^ ((lane >> 3) & 3);

  auto STAGE = [&](int buf, int ks) {
#pragma unroll
    for (int q = 0; q < 2; ++q) {
      int i = wid * 2 + q;
      int r = 16 * i + srow;
      const unsigned short* sa = gA + (size_t)r * kD + ks * BK + scch * 8;
      const unsigned short* sb = gB + (size_t)r * kD + ks * BK + scch * 8;
      __builtin_amdgcn_global_load_lds(
          (const __attribute__((address_space(1))) unsigned int*)sa,
          (__attribute__((address_space(3))) unsigned int*)&lA[buf][i * 512],
          16, 0, 0);
      __builtin_amdgcn_global_load_lds(
          (const __attribute__((address_space(1))) unsigned int*)sb,
          (__attribute__((address_space(3))) unsigned int*)&lB[buf][i * 512],
          16, 0, 0);
    }
  };

  // fragment-read lane offset (bytes): row r = 16m (+64wr) + (lane&15),
  // k-chunk s = lane>>4. All m-offsets become compile-time immediates.
  const int l15 = lane & 15;
  const int s4 = lane >> 4;
  const int laneoff = ((l15 >> 1) << 7) + ((l15 & 1) << 6) +
                      ((s4 ^ ((l15 >> 1) & 3)) << 4);

  f32x4 acc[4][4] = {};

  STAGE(0, 0);
  __syncthreads();

  int cur = 0;
  for (int ks = 0; ks < KSTEPS; ++ks) {
    if (ks + 1 < KSTEPS) STAGE(cur ^ 1, ks + 1);

    const char* Abase = (const char*)lA[cur] + wr * 4096 + laneoff;
    const char* Bbase = (const char*)lB[cur] + wc * 4096 + laneoff;
    s16x8 aF[4], bF[4];
#pragma unroll
    for (int m = 0; m < 4; ++m) aF[m] = *(const s16x8*)(Abase + m * 1024);
#pragma unroll
    for (int n = 0; n < 4; ++n) bF[n] = *(const s16x8*)(Bbase + n * 1024);
#pragma unroll
    for (int m = 0; m < 4; ++m)
#pragma unroll
      for (int n = 0; n < 4; ++n)
        acc[m][n] = __builtin_amdgcn_mfma_f32_16x16x32_bf16(
            aF[m], bF[n], acc[m][n], 0, 0, 0);

    __syncthreads();   // drains vmcnt+lgkmcnt: next buffer ready
    cur ^= 1;
  }

  // epilogue: L2 = sq_i + sq_j - 2*cross; 5-sigma kernel via repeated squaring
  const float sA = (ti < TILES / 2) ? 1.f : -1.f;
  const float sB = (tj < TILES / 2) ? 1.f : -1.f;
  const float scale = sA * sB * ((ti == tj) ? 1.f : 2.f) / 262144.f;  // /B^2
  const float* sqA = sq + c * kN + ti * BM;
  const float* sqB = sq + c * kN + tj * BM;

  float local = 0.f;
#pragma unroll
  for (int m = 0; m < 4; ++m) {
    float sqa_r[4];
#pragma unroll
    for (int rI = 0; rI < 4; ++rI)
      sqa_r[rI] = sqA[wr * 64 + m * 16 + (lane >> 4) * 4 + rI];
#pragma unroll
    for (int n = 0; n < 4; ++n) {
      float sqb_ = sqB[wc * 64 + n * 16 + (lane & 15)];
#pragma unroll
      for (int rI = 0; rI < 4; ++rI) {
        float L2 = sqa_r[rI] + sqb_ - 2.f * acc[m][n][rI];
        float tt = __expf(L2 * -0.0625f);  // exp(-L2/16)
        float t2 = tt * tt, t4 = t2 * t2, t8 = t4 * t4;
        local += tt + t2 + t4 + t8 + t8 * t8;
      }
    }
  }

#pragma unroll
  for (int o = 32; o > 0; o >>= 1) local += __shfl_down(local, o);
  if (lane == 0) wsum[wid] = local;
  __syncthreads();
  if (t == 0)
    atomicAdd(out, (wsum[0] + wsum[1] + wsum[2] + wsum[3]) * scale);
}

}  // namespace

extern "C" void kernel_launch(void* const* d_in, const int* in_sizes, int n_in,
                              void* d_out, int out_size, void* d_ws,
                              size_t ws_size, hipStream_t stream) {
  const float* src = (const float*)d_in[0];
  const float* tgt = (const float*)d_in[1];
  float* out = (float*)d_out;

  // workspace: [sq: 32*1024 f32 = 128 KiB][tot bf16: 32*1024*512*2B = 32 MiB]
  float* sq = (float*)d_ws;
  unsigned int* tot = (unsigned int*)((char*)d_ws + (size_t)kC * kN * 4);

  {
    int blocks = (kN * kC) / 4;   // one wave per (i,c) row, 4 waves/block
    prep_kernel<<<blocks, 256, 0, stream>>>(src, tgt, sq, tot, out);
  }
  {
    mmd_kernel<<<NPAIRS * kC, 256, 0, stream>>>((const unsigned short*)tot, sq, out);
  }
}

// Round 5
// 52.239 us; speedup vs baseline: 2.6870x; 1.0299x over previous
//
#include <hip/hip_runtime.h>

namespace {

constexpr int kC = 32;
constexpr int kD = 512;
constexpr int kB = 512;
constexpr int kN = 1024;               // 2B rows (source ++ target)
constexpr int kCD = kC * kD;           // floats per batch index i
constexpr int BM = 128;                // tile rows/cols
constexpr int BK = 32;                 // K chunk (bf16 elements)
constexpr int KSTEPS = kD / BK;        // 16
constexpr int TILES = kN / BM;         // 8
constexpr int NPAIRS = TILES * (TILES + 1) / 2;  // 36 (ti <= tj)

typedef float f32x4 __attribute__((ext_vector_type(4)));
typedef short s16x8 __attribute__((ext_vector_type(8)));

// pack two f32 to bf16 (RNE) into one u32: a -> low half, b -> high half
__device__ inline unsigned int pack_bf16(float a, float b) {
  unsigned int ua = __float_as_uint(a);
  unsigned int ub = __float_as_uint(b);
  ua += 0x7fffu + ((ua >> 16) & 1u);   // round-to-nearest-even
  ub += 0x7fffu + ((ub >> 16) & 1u);
  return (ua >> 16) | (ub & 0xffff0000u);
}

// Pass 1: tot[c][i][d] = bf16(total[i,c,d]); sq[c*kN+i] = sum_d total^2 (f32).
// One wave per (i,c) row of 512 floats. Also zeroes d_out (replaces memset).
__global__ void prep_kernel(const float* __restrict__ src,
                            const float* __restrict__ tgt,
                            float* __restrict__ sq,
                            unsigned int* __restrict__ tot,
                            float* __restrict__ out) {
  if (blockIdx.x == 0 && threadIdx.x == 0) *out = 0.f;
  int gw = (blockIdx.x * blockDim.x + threadIdx.x) >> 6;
  int lane = threadIdx.x & 63;
  int i = gw >> 5;
  int c = gw & 31;
  const float* p = (i < kB ? src + (size_t)i * kCD
                           : tgt + (size_t)(i - kB) * kCD) + c * kD;
  f32x4 v0 = *(const f32x4*)(p + lane * 8);
  f32x4 v1 = *(const f32x4*)(p + lane * 8 + 4);

  uint4 w = make_uint4(pack_bf16(v0.x, v0.y), pack_bf16(v0.z, v0.w),
                       pack_bf16(v1.x, v1.y), pack_bf16(v1.z, v1.w));
  *(uint4*)(tot + (size_t)(c * kN + i) * (kD / 2) + lane * 4) = w;

  float s = v0.x * v0.x + v0.y * v0.y + v0.z * v0.z + v0.w * v0.w
          + v1.x * v1.x + v1.y * v1.y + v1.z * v1.z + v1.w * v1.w;
#pragma unroll
  for (int o = 32; o > 0; o >>= 1) s += __shfl_down(s, o);
  if (lane == 0) sq[c * kN + i] = s;
}

// Pass 2: one block per (pair(ti<=tj), c); b%8 == c%8 pins channel -> XCD.
// LDS layout (per 8KB buffer, row r in 0..127, 16B chunk c in 0..3 of the
// 64B row): byte S(r,c) = (r>>1)*128 + (r&1)*64 + (c ^ ((r>>1)&3))*16.
// 3-deep buffering, stage-ahead-2, counted vmcnt(4) (T3+T4), setprio (T5).
__launch_bounds__(256, 3)
__global__ void mmd_kernel(const unsigned short* __restrict__ tot,
                           const float* __restrict__ sq,
                           float* __restrict__ out) {
  int b = blockIdx.x;
  int c = b & 31;           // b = pair*32 + c  -> b%8 == c%8 (XCD pin)
  int p = b >> 5;
  int ti = 0;
  while (p >= TILES - ti) { p -= TILES - ti; ++ti; }
  int tj = ti + p;

  __shared__ __align__(16) unsigned short lA[3][BM * BK];  // 3 x 8KB
  __shared__ __align__(16) unsigned short lB[3][BM * BK];
  __shared__ float wsum[4];

  const int t = threadIdx.x;
  const int lane = t & 63;
  const int wid = t >> 6;
  const int wr = wid >> 1;   // wave row (0..1)
  const int wc = wid & 1;    // wave col (0..1)

  const unsigned short* gA = tot + (size_t)(c * kN + ti * BM) * kD;
  const unsigned short* gB = tot + (size_t)(c * kN + tj * BM) * kD;

  // staging geometry: instr i covers LDS bytes [i*1024, +1024); lane l's 16B
  // at linear o=i*1024+l*16 holds global row r=16i+srow, chunk scch:
  const int srow = ((lane >> 3) << 1) + ((lane >> 2) & 1);
  const int scch = (lane & 3) ^ ((lane >> 3) & 3);

  auto STAGE = [&](int buf, int ks) {
#pragma unroll
    for (int q = 0; q < 2; ++q) {
      int i = wid * 2 + q;
      int r = 16 * i + srow;
      const unsigned short* sa = gA + (size_t)r * kD + ks * BK + scch * 8;
      const unsigned short* sb = gB + (size_t)r * kD + ks * BK + scch * 8;
      __builtin_amdgcn_global_load_lds(
          (const __attribute__((address_space(1))) unsigned int*)sa,
          (__attribute__((address_space(3))) unsigned int*)&lA[buf][i * 512],
          16, 0, 0);
      __builtin_amdgcn_global_load_lds(
          (const __attribute__((address_space(1))) unsigned int*)sb,
          (__attribute__((address_space(3))) unsigned int*)&lB[buf][i * 512],
          16, 0, 0);
    }
  };

  // fragment-read lane offset (bytes): row r = 16m (+64wr) + (lane&15),
  // k-chunk s = lane>>4. All m-offsets become compile-time immediates.
  const int l15 = lane & 15;
  const int s4 = lane >> 4;
  const int laneoff = ((l15 >> 1) << 7) + ((l15 & 1) << 6) +
                      ((s4 ^ ((l15 >> 1) & 3)) << 4);

  f32x4 acc[4][4] = {};

  STAGE(0, 0);
  STAGE(1, 1);

#pragma unroll
  for (int ks = 0; ks < KSTEPS; ++ks) {
    // wait for the OLDEST stage (this step's buffer) only; keep the next
    // stage's 4 loads in flight across the barrier (T4: never vmcnt(0)
    // mid-loop).
    if (ks + 1 < KSTEPS) asm volatile("s_waitcnt vmcnt(4)" ::: "memory");
    else                 asm volatile("s_waitcnt vmcnt(0)" ::: "memory");
    __builtin_amdgcn_sched_barrier(0);   // pin: nothing moves across
    __builtin_amdgcn_s_barrier();        // raw barrier: no implicit drain

    const int buf = ks % 3;
    const char* Abase = (const char*)lA[buf] + wr * 4096 + laneoff;
    const char* Bbase = (const char*)lB[buf] + wc * 4096 + laneoff;
    s16x8 aF[4], bF[4];
#pragma unroll
    for (int m = 0; m < 4; ++m) aF[m] = *(const s16x8*)(Abase + m * 1024);
#pragma unroll
    for (int n = 0; n < 4; ++n) bF[n] = *(const s16x8*)(Bbase + n * 1024);

    // overwrites buf (ks+2)%3 == (ks-1)%3: its last reads (iter ks-1) were
    // drained by their consuming MFMAs before this iter's pinned barrier.
    if (ks + 2 < KSTEPS) STAGE((ks + 2) % 3, ks + 2);

    __builtin_amdgcn_s_setprio(1);
#pragma unroll
    for (int m = 0; m < 4; ++m)
#pragma unroll
      for (int n = 0; n < 4; ++n)
        acc[m][n] = __builtin_amdgcn_mfma_f32_16x16x32_bf16(
            aF[m], bF[n], acc[m][n], 0, 0, 0);
    __builtin_amdgcn_s_setprio(0);
  }

  // epilogue: L2 = sq_i + sq_j - 2*cross; 5-sigma kernel via repeated squaring
  const float sA = (ti < TILES / 2) ? 1.f : -1.f;
  const float sB = (tj < TILES / 2) ? 1.f : -1.f;
  const float scale = sA * sB * ((ti == tj) ? 1.f : 2.f) / 262144.f;  // /B^2
  const float* sqA = sq + c * kN + ti * BM;
  const float* sqB = sq + c * kN + tj * BM;

  float local = 0.f;
#pragma unroll
  for (int m = 0; m < 4; ++m) {
    float sqa_r[4];
#pragma unroll
    for (int rI = 0; rI < 4; ++rI)
      sqa_r[rI] = sqA[wr * 64 + m * 16 + (lane >> 4) * 4 + rI];
#pragma unroll
    for (int n = 0; n < 4; ++n) {
      float sqb_ = sqB[wc * 64 + n * 16 + (lane & 15)];
#pragma unroll
      for (int rI = 0; rI < 4; ++rI) {
        float L2 = sqa_r[rI] + sqb_ - 2.f * acc[m][n][rI];
        float tt = __expf(L2 * -0.0625f);  // exp(-L2/16)
        float t2 = tt * tt, t4 = t2 * t2, t8 = t4 * t4;
        local += tt + t2 + t4 + t8 + t8 * t8;
      }
    }
  }

#pragma unroll
  for (int o = 32; o > 0; o >>= 1) local += __shfl_down(local, o);
  if (lane == 0) wsum[wid] = local;
  __syncthreads();
  if (t == 0)
    atomicAdd(out, (wsum[0] + wsum[1] + wsum[2] + wsum[3]) * scale);
}

}  // namespace

extern "C" void kernel_launch(void* const* d_in, const int* in_sizes, int n_in,
                              void* d_out, int out_size, void* d_ws,
                              size_t ws_size, hipStream_t stream) {
  const float* src = (const float*)d_in[0];
  const float* tgt = (const float*)d_in[1];
  float* out = (float*)d_out;

  // workspace: [sq: 32*1024 f32 = 128 KiB][tot bf16: 32*1024*512*2B = 32 MiB]
  float* sq = (float*)d_ws;
  unsigned int* tot = (unsigned int*)((char*)d_ws + (size_t)kC * kN * 4);

  {
    int blocks = (kN * kC) / 4;   // one wave per (i,c) row, 4 waves/block
    prep_kernel<<<blocks, 256, 0, stream>>>(src, tgt, sq, tot, out);
  }
  {
    mmd_kernel<<<NPAIRS * kC, 256, 0, stream>>>((const unsigned short*)tot, sq, out);
  }
}